// Round 10
// baseline (74.641 us; speedup 1.0000x reference)
//
#include <hip/hip_runtime.h>
#include <math.h>

#define CC    8
#define TFN   512
#define TGN   2048
#define HN    64
#define QB    8                 // solve blocks per condition
#define RB    64                // rows per solve block
#define NPREP  (CC * TFN)       // 4096
#define NEPI   64
#define NSOLVE (CC * QB)        // 64
#define MAGICY 0x59A17EC1u
#define MAGICW 0x3C0FFEE5u

// ---- bf16 helper (manual, RNE) ----
__device__ __forceinline__ unsigned short f2bf(float f) {
    unsigned int u = __float_as_uint(f);
    unsigned int r = (u + 0x7fffu + ((u >> 16) & 1u)) >> 16;
    return (unsigned short)r;
}
__device__ __forceinline__ float lo32f(unsigned long long v) {
    return __uint_as_float((unsigned int)v);
}

// ============================================================================
// ONE kernel, three roles by blockIdx (solve blocks LAST -> dispatched last,
// prep never waits on anyone -> no deadlock):
//  [0, 4096):      prep row (c,i): y (tagged u64 publish), y2, A_S row -> bf16
//                  via relaxed ATOMIC dword stores (LLC-resident, no L2
//                  coherence issues), tag store is RELEASE (orders A2 stores).
//  [4096, 4160):   baseline epilogue for NON-TF genes (binary-search skip).
//  [4160, 4224):   Neumann solve (NITER=2), 8 blocks/condition, A-slice in
//                  regs; y-wait and w1-exchange both via tagged-u64 RMW polls.
// ============================================================================
__global__ __launch_bounds__(256) void fused_kernel(
    const float* __restrict__ z, const float* __restrict__ grn,
    const int* __restrict__ tf,
    const float* __restrict__ wz, const float* __restrict__ bz,
    const float* __restrict__ w1, const float* __restrict__ b1,
    const float* __restrict__ w2, const float* __restrict__ b2,
    float* __restrict__ out,
    unsigned int* __restrict__ A2,
    unsigned long long* __restrict__ yT, float* __restrict__ y2X,
    unsigned long long* __restrict__ w1T, unsigned long long* __restrict__ w2T)
{
    const int b   = blockIdx.x;
    const int tid = threadIdx.x;

    if (b < NPREP) {
        // ================= prep row =================
        __shared__ float row[TGN];
        __shared__ int   tfs[TFN];
        __shared__ float red[8];
        const int c = b >> 9;

        const float4* g4 = (const float4*)(grn + (size_t)b * TGN);
        const float4* z4 = (const float4*)(z + c * TGN);
        float4* r4 = (float4*)row;

        float accy = 0.f, accs = 0.f;
        for (int k = tid; k < TGN / 4; k += 256) {
            float4 g = g4[k];
            float4 zz = z4[k];
            r4[k] = g;
            accy += g.x * zz.x + g.y * zz.y + g.z * zz.z + g.w * zz.w;
            accs += g.x + g.y + g.z + g.w;
        }
        for (int k = tid; k < TFN; k += 256) {
            int t = tf[c * TFN + k];
            tfs[k] = t < 0 ? 0 : (t >= TGN ? TGN - 1 : t);
        }
        for (int off = 32; off > 0; off >>= 1) {
            accy += __shfl_down(accy, off);
            accs += __shfl_down(accs, off);
        }
        const int wave = tid >> 6, lane = tid & 63;
        if (lane == 0) { red[wave] = accy; red[4 + wave] = accs; }
        __syncthreads();   // row[] staged, red[] ready

        // A_S row -> bf16, atomic dword stores, layout for solve:
        // q=i_row>>6, r=i_row&63; pair d: off=(c*8+q)*16384 + (d>>2)*256 + r*4 + (d&3)
        const int i_row = b & 511;
        const int q = i_row >> 6, r = i_row & 63;
        const size_t base = (size_t)(c * QB + q) * 16384 + r * 4;
        const int d = tid;
        unsigned int lo = f2bf(row[tfs[2 * d]]);
        unsigned int hi = f2bf(row[tfs[2 * d + 1]]);
        __hip_atomic_store(&A2[base + (size_t)(d >> 2) * 256 + (d & 3)],
                           lo | (hi << 16), __ATOMIC_RELAXED, __HIP_MEMORY_SCOPE_AGENT);
        float yv = 0.f;
        if (tid == 0) {
            yv = red[0] + red[1] + red[2] + red[3];
            float y2v = red[4] + red[5] + red[6] + red[7];
            __hip_atomic_store(&y2X[b], y2v, __ATOMIC_RELAXED, __HIP_MEMORY_SCOPE_AGENT);
        }
        __syncthreads();   // every wave drains vmcnt(0) -> A2/y2 stores at LLC
        if (tid == 0) {
            __hip_atomic_store(&yT[b],
                ((unsigned long long)MAGICY << 32) |
                 (unsigned long long)__float_as_uint(yv),
                __ATOMIC_RELEASE, __HIP_MEMORY_SCOPE_AGENT);
        }
    } else if (b < NPREP + NEPI) {
        // ================= baseline epilogue (non-TF genes only) =================
        __shared__ float sv1[HN], su1[HN], sb1s[HN], sw20[HN], sw21[HN], sb2v[2];
        __shared__ int   tfs[TFN];
        const int eb  = b - NPREP;         // 0..63
        const int gid = eb * 256 + tid;    // 0..16383
        const int c   = gid >> 11;
        for (int k = tid; k < TFN; k += 256) tfs[k] = tf[c * TFN + k];
        if (tid < HN) {
            float a = 0.f, bb = 0.f;
            const float4* w14 = (const float4*)(w1 + tid * HN);
            const float4* wz4 = (const float4*)wz;
            const float4* bz4 = (const float4*)bz;
#pragma unroll
            for (int h4 = 0; h4 < HN / 4; ++h4) {
                float4 w = w14[h4], a4 = wz4[h4], b4 = bz4[h4];
                a  += w.x * a4.x + w.y * a4.y + w.z * a4.z + w.w * a4.w;
                bb += w.x * b4.x + w.y * b4.y + w.z * b4.z + w.w * b4.w;
            }
            sv1[tid] = a; su1[tid] = bb;
            sb1s[tid] = b1[tid]; sw20[tid] = w2[tid]; sw21[tid] = w2[HN + tid];
            if (tid < 2) sb2v[tid] = b2[tid];
        }
        __syncthreads();
        const int g = gid & (TGN - 1);
        int lo = 0, hi = TFN;
        while (lo < hi) { int m = (lo + hi) >> 1; if (tfs[m] < g) lo = m + 1; else hi = m; }
        const bool isTF = (lo < TFN && tfs[lo] == g);
        if (!isTF) {
            const float s = z[gid];
            float a0 = 0.f, a1 = 0.f;
#pragma unroll
            for (int o = 0; o < HN; ++o) {
                float pre = fmaf(s, sv1[o], su1[o] + sb1s[o]);   // s2 = 1
                float h = fmaxf(pre, 0.f);
                a0 = fmaf(sw20[o], h, a0);
                a1 = fmaf(sw21[o], h, a1);
            }
            const float mu = a0 + sb2v[0];
            const float x  = a1 + sb2v[1];
            const float sp = fmaxf(x, 0.f) + log1pf(expf(-fabsf(x)));
            out[gid]            = mu;
            out[CC * TGN + gid] = sp + 1e-6f;
        }
    } else {
        // ================= solve (dispatched last) =================
        __shared__ float w_lds[TFN], w2_lds[TFN];
        __shared__ float sv1[HN], su1[HN], sb1s[HN], sw20[HN], sw21[HN], sb2v[2];
        __shared__ int   tfs_own[RB];
        __shared__ float sS[RB], sS2[RB];
        __shared__ unsigned int snz;

        const int sb = b - (NPREP + NEPI);
        const int c = sb >> 3, q = sb & 7;
        const int r = tid >> 2, cb = tid & 3;   // 64 rows x 4 threads/row
        const int row0 = q * RB;

        if (tid < HN) {
            float a = 0.f, bb = 0.f;
            const float4* w14 = (const float4*)(w1 + tid * HN);
            const float4* wz4 = (const float4*)wz;
            const float4* bz4 = (const float4*)bz;
#pragma unroll
            for (int h4 = 0; h4 < HN / 4; ++h4) {
                float4 w = w14[h4], a4 = wz4[h4], b4 = bz4[h4];
                a  += w.x * a4.x + w.y * a4.y + w.z * a4.z + w.w * a4.w;
                bb += w.x * b4.x + w.y * b4.y + w.z * b4.z + w.w * b4.w;
            }
            sv1[tid] = a; su1[tid] = bb;
            sb1s[tid] = b1[tid]; sw20[tid] = w2[tid]; sw21[tid] = w2[HN + tid];
            if (tid < 2) sb2v[tid] = b2[tid];
            unsigned long long m = __ballot(bz[tid] != 0.f);
            if (tid == 0) snz = (m != 0ULL) ? 1u : 0u;
        }
        if (tid < RB) {
            int v = tf[c * TFN + row0 + tid];
            tfs_own[tid] = v < 0 ? 0 : (v >= TGN ? TGN - 1 : v);
        }
        __syncthreads();
        const bool has2 = (snz != 0u);

        // ---- wait for all 512 y tags of this condition ----
        if (tid < 64) {
            for (int k = 0; k < 8; ++k) {
                unsigned long long* p = &yT[c * TFN + tid * 8 + k];
                int polls = 0;
                while ((unsigned int)(__hip_atomic_fetch_add(p, 0ULL,
                        __ATOMIC_RELAXED, __HIP_MEMORY_SCOPE_AGENT) >> 32) != MAGICY) {
                    __builtin_amdgcn_s_sleep(2);
                    if (++polls > (1 << 20)) break;
                }
            }
        }
        __syncthreads();
        // ---- fill y into LDS (atomic loads: fresh from LLC) ----
        {
            unsigned long long v0 = __hip_atomic_load(&yT[c * TFN + tid],
                                    __ATOMIC_RELAXED, __HIP_MEMORY_SCOPE_AGENT);
            unsigned long long v1 = __hip_atomic_load(&yT[c * TFN + 256 + tid],
                                    __ATOMIC_RELAXED, __HIP_MEMORY_SCOPE_AGENT);
            w_lds[tid] = lo32f(v0); w_lds[256 + tid] = lo32f(v1);
            if (has2) {
                w2_lds[tid] = __hip_atomic_load(&y2X[c * TFN + tid],
                              __ATOMIC_RELAXED, __HIP_MEMORY_SCOPE_AGENT);
                w2_lds[256 + tid] = __hip_atomic_load(&y2X[c * TFN + 256 + tid],
                              __ATOMIC_RELAXED, __HIP_MEMORY_SCOPE_AGENT);
            }
        }
        __syncthreads();
        const float myY  = w_lds[row0 + r];
        const float myY2 = has2 ? w2_lds[row0 + r] : 0.f;

        // ---- A slice -> registers (A2 visible: tags were released after it) ----
        unsigned int areg[64];
        const unsigned int* Ab = A2 + (size_t)(c * QB + q) * 16384 + r * 4 + cb;
#pragma unroll
        for (int i = 0; i < 64; ++i) areg[i] = Ab[(size_t)i * 256];

        float wv = 0.f, w2v = 0.f;
        // ---- mv1: w1 = y + A y ----
        {
            float a1 = 0.f, a2 = 0.f;
#pragma unroll
            for (int i = 0; i < 64; ++i) {
                unsigned int ad = areg[i];
                float alo = __uint_as_float(ad << 16);
                float ahi = __uint_as_float(ad & 0xffff0000u);
                const float2 wp = *(const float2*)&w_lds[2 * (cb + 4 * i)];
                a1 = fmaf(alo, wp.x, a1);
                a1 = fmaf(ahi, wp.y, a1);
                if (has2) {
                    const float2 wq = *(const float2*)&w2_lds[2 * (cb + 4 * i)];
                    a2 = fmaf(alo, wq.x, a2);
                    a2 = fmaf(ahi, wq.y, a2);
                }
            }
            a1 += __shfl_down(a1, 2, 4); a1 += __shfl_down(a1, 1, 4);
            if (has2) { a2 += __shfl_down(a2, 2, 4); a2 += __shfl_down(a2, 1, 4); }
            if (cb == 0) { wv = myY + a1; if (has2) w2v = myY2 + a2; }
        }
        // ---- publish w1 (tagged; release orders the optional w2 store) ----
        if (cb == 0) {
            if (has2)
                __hip_atomic_store(&w2T[c * TFN + row0 + r],
                    ((unsigned long long)MAGICW << 32) |
                     (unsigned long long)__float_as_uint(w2v),
                    __ATOMIC_RELAXED, __HIP_MEMORY_SCOPE_AGENT);
            __hip_atomic_store(&w1T[c * TFN + row0 + r],
                ((unsigned long long)MAGICW << 32) |
                 (unsigned long long)__float_as_uint(wv),
                __ATOMIC_RELEASE, __HIP_MEMORY_SCOPE_AGENT);
        }
        // ---- wait for all 512 w1 tags ----
        if (tid < 64) {
            for (int k = 0; k < 8; ++k) {
                unsigned long long* p = &w1T[c * TFN + tid * 8 + k];
                int polls = 0;
                while ((unsigned int)(__hip_atomic_fetch_add(p, 0ULL,
                        __ATOMIC_RELAXED, __HIP_MEMORY_SCOPE_AGENT) >> 32) != MAGICW) {
                    __builtin_amdgcn_s_sleep(1);
                    if (++polls > (1 << 20)) break;
                }
            }
        }
        __syncthreads();
        {
            unsigned long long v0 = __hip_atomic_load(&w1T[c * TFN + tid],
                                    __ATOMIC_RELAXED, __HIP_MEMORY_SCOPE_AGENT);
            unsigned long long v1 = __hip_atomic_load(&w1T[c * TFN + 256 + tid],
                                    __ATOMIC_RELAXED, __HIP_MEMORY_SCOPE_AGENT);
            w_lds[tid] = lo32f(v0); w_lds[256 + tid] = lo32f(v1);
            if (has2) {
                unsigned long long u0 = __hip_atomic_load(&w2T[c * TFN + tid],
                                        __ATOMIC_RELAXED, __HIP_MEMORY_SCOPE_AGENT);
                unsigned long long u1 = __hip_atomic_load(&w2T[c * TFN + 256 + tid],
                                        __ATOMIC_RELAXED, __HIP_MEMORY_SCOPE_AGENT);
                w2_lds[tid] = lo32f(u0); w2_lds[256 + tid] = lo32f(u1);
            }
        }
        __syncthreads();
        // ---- mv2: w = y + A w1 ----
        {
            float a1 = 0.f, a2 = 0.f;
#pragma unroll
            for (int i = 0; i < 64; ++i) {
                unsigned int ad = areg[i];
                float alo = __uint_as_float(ad << 16);
                float ahi = __uint_as_float(ad & 0xffff0000u);
                const float2 wp = *(const float2*)&w_lds[2 * (cb + 4 * i)];
                a1 = fmaf(alo, wp.x, a1);
                a1 = fmaf(ahi, wp.y, a1);
                if (has2) {
                    const float2 wq = *(const float2*)&w2_lds[2 * (cb + 4 * i)];
                    a2 = fmaf(alo, wq.x, a2);
                    a2 = fmaf(ahi, wq.y, a2);
                }
            }
            a1 += __shfl_down(a1, 2, 4); a1 += __shfl_down(a1, 1, 4);
            if (has2) { a2 += __shfl_down(a2, 2, 4); a2 += __shfl_down(a2, 1, 4); }
            if (cb == 0) { wv = myY + a1; if (has2) w2v = myY2 + a2; }
        }
        // ---- TF-gene epilogue (own 64 rows; 4 threads/gene, 16 h each) ----
        if (cb == 0) {
            int g = tfs_own[r];
            sS[r]  = z[c * TGN + g] + wv;
            sS2[r] = has2 ? (1.f + w2v) : 1.f;
        }
        __syncthreads();
        const float s = sS[r], s2 = sS2[r];
        float a0 = 0.f, a1e = 0.f;
#pragma unroll
        for (int oo = 0; oo < 16; ++oo) {
            int o = cb * 16 + oo;
            float pre = fmaf(s, sv1[o], fmaf(s2, su1[o], sb1s[o]));
            float h = fmaxf(pre, 0.f);
            a0  = fmaf(sw20[o], h, a0);
            a1e = fmaf(sw21[o], h, a1e);
        }
        a0  += __shfl_down(a0, 2, 4);  a0  += __shfl_down(a0, 1, 4);
        a1e += __shfl_down(a1e, 2, 4); a1e += __shfl_down(a1e, 1, 4);
        if (cb == 0) {
            int g = tfs_own[r];
            float mu = a0 + sb2v[0];
            float x  = a1e + sb2v[1];
            float sp = fmaxf(x, 0.f) + log1pf(expf(-fabsf(x)));
            out[c * TGN + g]            = mu;
            out[CC * TGN + c * TGN + g] = sp + 1e-6f;
        }
    }
}

extern "C" void kernel_launch(void* const* d_in, const int* in_sizes, int n_in,
                              void* d_out, int out_size, void* d_ws, size_t ws_size,
                              hipStream_t stream)
{
    const float* z   = (const float*)d_in[0];
    const float* grn = (const float*)d_in[1];
    const int*   tf  = (const int*)d_in[2];
    const float* wz  = (const float*)d_in[4];
    const float* bz  = (const float*)d_in[5];
    const float* w1  = (const float*)d_in[6];
    const float* b1  = (const float*)d_in[7];
    const float* w2  = (const float*)d_in[8];
    const float* b2  = (const float*)d_in[9];
    float* out = (float*)d_out;

    char* ws = (char*)d_ws;
    unsigned int*       A2  = (unsigned int*)ws;                        // 4 MB
    unsigned long long* yT  = (unsigned long long*)(ws + 4194304);     // 32 KB
    unsigned long long* w1T = (unsigned long long*)(ws + 4227072);     // 32 KB
    unsigned long long* w2T = (unsigned long long*)(ws + 4259840);     // 32 KB
    float*              y2X = (float*)(ws + 4292608);                  // 16 KB

    fused_kernel<<<NPREP + NEPI + NSOLVE, 256, 0, stream>>>(
        z, grn, tf, wz, bz, w1, b1, w2, b2, out, A2, yT, y2X, w1T, w2T);
}

// Round 11
// 23.176 us; speedup vs baseline: 3.2207x; 3.2207x over previous
//
#include <hip/hip_runtime.h>
#include <math.h>

#define CC    8
#define TFN   512
#define TGN   2048
#define HN    64
#define QB    8      // solve blocks per condition
#define RB    64     // rows per solve block
#define PB    2048   // prep blocks (2 grn rows each)

// ---- bf16 helper (manual, RNE) ----
__device__ __forceinline__ unsigned short f2bf(float f) {
    unsigned int u = __float_as_uint(f);
    unsigned int r = (u + 0x7fffu + ((u >> 16) & 1u)) >> 16;
    return (unsigned short)r;
}

// ============================================================================
// K1: prep (2 rows/block) + baseline epilogue + counter zeroing.
//   blocks [0, 2048):      grn rows 2b, 2b+1: y, y2 (fp32), A_S rows -> bf16,
//                          swizzled for the QB=8/RB=64 solve layout
//   blocks [2048, 2112):   baseline epi for all genes (s=z, s2=1)
//   block  2112:           zero the per-condition sync counters
// ============================================================================
__global__ __launch_bounds__(256) void prep_kernel(
    const float* __restrict__ z, const float* __restrict__ grn,
    const int* __restrict__ tf,
    const float* __restrict__ wz, const float* __restrict__ bz,
    const float* __restrict__ w1, const float* __restrict__ b1,
    const float* __restrict__ w2, const float* __restrict__ b2,
    float* __restrict__ out,
    unsigned int* __restrict__ A2, float* __restrict__ y, float* __restrict__ y2,
    unsigned int* __restrict__ cnt)
{
    const int b   = blockIdx.x;
    const int tid = threadIdx.x;

    if (b < PB) {
        // ---------------- prep: 2 grn rows ----------------
        __shared__ float row0s[TGN], row1s[TGN];     // 16 KB
        __shared__ int   tfs[TFN];
        __shared__ float redY[2][4], redS[2][4];
        const int c = b >> 8;                         // 256 blocks per condition

        const float4* z4  = (const float4*)(z + c * TGN);
        const float4* g40 = (const float4*)(grn + (size_t)(2 * b) * TGN);
        const float4* g41 = (const float4*)(grn + (size_t)(2 * b + 1) * TGN);

        float ay0 = 0.f, as0 = 0.f, ay1 = 0.f, as1 = 0.f;
        for (int k = tid; k < TGN / 4; k += 256) {
            float4 zz = z4[k];
            float4 g0 = g40[k];
            float4 g1 = g41[k];
            ((float4*)row0s)[k] = g0;
            ((float4*)row1s)[k] = g1;
            ay0 += g0.x * zz.x + g0.y * zz.y + g0.z * zz.z + g0.w * zz.w;
            as0 += g0.x + g0.y + g0.z + g0.w;
            ay1 += g1.x * zz.x + g1.y * zz.y + g1.z * zz.z + g1.w * zz.w;
            as1 += g1.x + g1.y + g1.z + g1.w;
        }
        for (int k = tid; k < TFN; k += 256) {
            int t = tf[c * TFN + k];
            tfs[k] = t < 0 ? 0 : (t >= TGN ? TGN - 1 : t);
        }
        for (int off = 32; off > 0; off >>= 1) {
            ay0 += __shfl_down(ay0, off);
            as0 += __shfl_down(as0, off);
            ay1 += __shfl_down(ay1, off);
            as1 += __shfl_down(as1, off);
        }
        const int wave = tid >> 6, lane = tid & 63;
        if (lane == 0) {
            redY[0][wave] = ay0; redY[1][wave] = ay1;
            redS[0][wave] = as0; redS[1][wave] = as1;
        }
        __syncthreads();
        if (tid < 2) {
            y[2 * b + tid]  = redY[tid][0] + redY[tid][1] + redY[tid][2] + redY[tid][3];
            y2[2 * b + tid] = redS[tid][0] + redS[tid][1] + redS[tid][2] + redS[tid][3];
        }
        // A_S rows -> bf16, swizzled: q=i_row>>6, r=i_row&63;
        // dword d: off = (c*8+q)*16384 + (d>>4)*1024 + r*16 + (d&15)
        const int d = tid;
        {
            const int i_row = (2 * b) & 511;
            const int q = i_row >> 6, r = i_row & 63;
            const size_t base = (size_t)(c * QB + q) * 16384 + r * 16;
            unsigned int lo = f2bf(row0s[tfs[2 * d]]);
            unsigned int hi = f2bf(row0s[tfs[2 * d + 1]]);
            A2[base + (size_t)(d >> 4) * 1024 + (d & 15)] = lo | (hi << 16);
        }
        {
            const int i_row = (2 * b + 1) & 511;
            const int q = i_row >> 6, r = i_row & 63;
            const size_t base = (size_t)(c * QB + q) * 16384 + r * 16;
            unsigned int lo = f2bf(row1s[tfs[2 * d]]);
            unsigned int hi = f2bf(row1s[tfs[2 * d + 1]]);
            A2[base + (size_t)(d >> 4) * 1024 + (d & 15)] = lo | (hi << 16);
        }
    } else if (b < PB + 64) {
        // ---------------- baseline epi (all genes) ----------------
        __shared__ float sv1[HN], su1[HN], sb1s[HN], sw20[HN], sw21[HN], sb2v[2];
        if (tid < HN) {
            float a = 0.f, bb = 0.f;
            const float4* w14 = (const float4*)(w1 + tid * HN);
            const float4* wz4 = (const float4*)wz;
            const float4* bz4 = (const float4*)bz;
#pragma unroll
            for (int h4 = 0; h4 < HN / 4; ++h4) {
                float4 w = w14[h4], a4 = wz4[h4], b4 = bz4[h4];
                a  += w.x * a4.x + w.y * a4.y + w.z * a4.z + w.w * a4.w;
                bb += w.x * b4.x + w.y * b4.y + w.z * b4.z + w.w * b4.w;
            }
            sv1[tid] = a; su1[tid] = bb;
            sb1s[tid] = b1[tid]; sw20[tid] = w2[tid]; sw21[tid] = w2[HN + tid];
            if (tid < 2) sb2v[tid] = b2[tid];
        }
        __syncthreads();
        const int gid = (b - PB) * 256 + tid;   // 0..16383
        const float s = z[gid];
        float a0 = 0.f, a1 = 0.f;
#pragma unroll
        for (int o = 0; o < HN; ++o) {
            float pre = fmaf(s, sv1[o], su1[o] + sb1s[o]);   // s2 = 1
            float h = fmaxf(pre, 0.f);
            a0 = fmaf(sw20[o], h, a0);
            a1 = fmaf(sw21[o], h, a1);
        }
        const float mu = a0 + sb2v[0];
        const float x  = a1 + sb2v[1];
        const float sp = fmaxf(x, 0.f) + log1pf(expf(-fabsf(x)));
        out[gid]            = mu;
        out[CC * TGN + gid] = sp + 1e-6f;
    } else {
        if (tid < 128)
            __hip_atomic_store(&cnt[tid], 0u, __ATOMIC_RELAXED, __HIP_MEMORY_SCOPE_AGENT);
    }
}

// ============================================================================
// K2: Neumann solve (NITER=2 -> ONE cross-block sync), 8 blocks/condition,
// A_S bf16 in registers. The epilogue-weight dots, tf load, and z-gather
// prefetch are placed BETWEEN publish and poll to hide the sync latency.
// ============================================================================
__global__ __launch_bounds__(1024) void solve_kernel(
    const float* __restrict__ z, const int* __restrict__ tf,
    const float* __restrict__ wz, const float* __restrict__ bz,
    const float* __restrict__ w1, const float* __restrict__ b1,
    const float* __restrict__ w2, const float* __restrict__ b2,
    float* __restrict__ out,
    const unsigned int* __restrict__ A2,
    const float* __restrict__ y, const float* __restrict__ y2,
    float* __restrict__ wX, float* __restrict__ w2X,
    unsigned int* __restrict__ cnt)
{
    __shared__ float w_lds[TFN];
    __shared__ float w2_lds[TFN];
    __shared__ float sv1[HN], su1[HN], sb1s[HN], sw20[HN], sw21[HN], sb2v[2];
    __shared__ int   tfs_own[RB];
    __shared__ float sSz[RB], sS[RB], sS2[RB];
    __shared__ unsigned int snz;

    const int b = blockIdx.x;
    const int c = b >> 3, q = b & 7;
    const int t = threadIdx.x;
    const int r = t >> 4, cb = t & 15;    // 64 rows x 16 threads/row
    const int row0 = q * RB;

    // A slice -> registers: areg[i] = cols {2(cb+16i), 2(cb+16i)+1} of row row0+r
    unsigned int areg[16];
    const unsigned int* Ab = A2 + (size_t)(c * QB + q) * 16384 + r * 16 + cb;
#pragma unroll
    for (int i = 0; i < 16; ++i) areg[i] = Ab[(size_t)i * 1024];

    if (t < TFN) {
        w_lds[t]  = y[c * TFN + t];
        w2_lds[t] = y2[c * TFN + t];
    }
    if (t < HN) {
        unsigned long long m = __ballot(bz[t] != 0.f);
        if (t == 0) snz = (m != 0ULL) ? 1u : 0u;
    }
    __syncthreads();

    const bool has2 = (snz != 0u);
    const float myY  = w_lds[row0 + r];
    const float myY2 = has2 ? w2_lds[row0 + r] : 0.f;

    float wv = 0.f, w2v = 0.f;   // valid in cb==0 lanes

    // ---- mv1: w1 = y + A y ----
    {
        float a1 = 0.f, a2 = 0.f;
        if (has2) {
#pragma unroll
            for (int i = 0; i < 16; ++i) {
                unsigned int ad = areg[i];
                float alo = __uint_as_float(ad << 16);
                float ahi = __uint_as_float(ad & 0xffff0000u);
                float2 wp = *(const float2*)&w_lds[2 * (cb + 16 * i)];
                float2 wq = *(const float2*)&w2_lds[2 * (cb + 16 * i)];
                a1 = fmaf(alo, wp.x, a1);
                a1 = fmaf(ahi, wp.y, a1);
                a2 = fmaf(alo, wq.x, a2);
                a2 = fmaf(ahi, wq.y, a2);
            }
        } else {
#pragma unroll
            for (int i = 0; i < 16; ++i) {
                unsigned int ad = areg[i];
                float alo = __uint_as_float(ad << 16);
                float ahi = __uint_as_float(ad & 0xffff0000u);
                float2 wp = *(const float2*)&w_lds[2 * (cb + 16 * i)];
                a1 = fmaf(alo, wp.x, a1);
                a1 = fmaf(ahi, wp.y, a1);
            }
        }
        a1 += __shfl_down(a1, 8, 16); a1 += __shfl_down(a1, 4, 16);
        a1 += __shfl_down(a1, 2, 16); a1 += __shfl_down(a1, 1, 16);
        if (has2) {
            a2 += __shfl_down(a2, 8, 16); a2 += __shfl_down(a2, 4, 16);
            a2 += __shfl_down(a2, 2, 16); a2 += __shfl_down(a2, 1, 16);
        }
        if (cb == 0) {
            wv = myY + a1;
            if (has2) w2v = myY2 + a2;
        }
    }

    // ---- publish own 64 w1 values (LLC-resident atomics) ----
    if (cb == 0) {
        __hip_atomic_store(&wX[c * TFN + row0 + r], wv,
                           __ATOMIC_RELAXED, __HIP_MEMORY_SCOPE_AGENT);
        if (has2)
            __hip_atomic_store(&w2X[c * TFN + row0 + r], w2v,
                               __ATOMIC_RELAXED, __HIP_MEMORY_SCOPE_AGENT);
    }
    __syncthreads();   // vmcnt(0) drain -> stores completed at LLC
    if (t == 0)
        __hip_atomic_fetch_add(&cnt[c * 16], 1u,
                               __ATOMIC_RELAXED, __HIP_MEMORY_SCOPE_AGENT);

    // ---- OVERLAP: epilogue weights + tf + z-gather while others publish ----
    if (t < HN) {
        float a = 0.f, bb = 0.f;
        const float4* w14 = (const float4*)(w1 + t * HN);
        const float4* wz4 = (const float4*)wz;
        const float4* bz4 = (const float4*)bz;
#pragma unroll
        for (int h4 = 0; h4 < HN / 4; ++h4) {
            float4 w = w14[h4], a4 = wz4[h4], b4 = bz4[h4];
            a  += w.x * a4.x + w.y * a4.y + w.z * a4.z + w.w * a4.w;
            bb += w.x * b4.x + w.y * b4.y + w.z * b4.z + w.w * b4.w;
        }
        sv1[t] = a; su1[t] = bb;
        sb1s[t] = b1[t]; sw20[t] = w2[t]; sw21[t] = w2[HN + t];
        if (t < 2) sb2v[t] = b2[t];
    }
    if (t < RB) {
        int v = tf[c * TFN + row0 + t];
        tfs_own[t] = v < 0 ? 0 : (v >= TGN ? TGN - 1 : v);
    }
    __syncthreads();                          // tfs_own visible
    if (cb == 0) sSz[r] = z[c * TGN + tfs_own[r]];   // gather prefetch

    // ---- poll: one poller thread per block waits for all 8 publishes ----
    if (t == 0) {
        unsigned int* pc = &cnt[c * 16];
        int polls = 0;
        while (__hip_atomic_fetch_add(pc, 0u, __ATOMIC_RELAXED,
                                      __HIP_MEMORY_SCOPE_AGENT) < (unsigned int)QB) {
            __builtin_amdgcn_s_sleep(1);
            if (++polls > (1 << 22)) break;
        }
    }
    __syncthreads();
    // ---- bulk re-read of the full w1 vector (atomic loads: fresh from LLC) ----
    if (t < TFN)
        w_lds[t] = __hip_atomic_load(&wX[c * TFN + t],
                                     __ATOMIC_RELAXED, __HIP_MEMORY_SCOPE_AGENT);
    else if (has2)
        w2_lds[t - TFN] = __hip_atomic_load(&w2X[c * TFN + (t - TFN)],
                                            __ATOMIC_RELAXED, __HIP_MEMORY_SCOPE_AGENT);
    __syncthreads();

    // ---- mv2: w = y + A w1 ----
    {
        float a1 = 0.f, a2 = 0.f;
        if (has2) {
#pragma unroll
            for (int i = 0; i < 16; ++i) {
                unsigned int ad = areg[i];
                float alo = __uint_as_float(ad << 16);
                float ahi = __uint_as_float(ad & 0xffff0000u);
                float2 wp = *(const float2*)&w_lds[2 * (cb + 16 * i)];
                float2 wq = *(const float2*)&w2_lds[2 * (cb + 16 * i)];
                a1 = fmaf(alo, wp.x, a1);
                a1 = fmaf(ahi, wp.y, a1);
                a2 = fmaf(alo, wq.x, a2);
                a2 = fmaf(ahi, wq.y, a2);
            }
        } else {
#pragma unroll
            for (int i = 0; i < 16; ++i) {
                unsigned int ad = areg[i];
                float alo = __uint_as_float(ad << 16);
                float ahi = __uint_as_float(ad & 0xffff0000u);
                float2 wp = *(const float2*)&w_lds[2 * (cb + 16 * i)];
                a1 = fmaf(alo, wp.x, a1);
                a1 = fmaf(ahi, wp.y, a1);
            }
        }
        a1 += __shfl_down(a1, 8, 16); a1 += __shfl_down(a1, 4, 16);
        a1 += __shfl_down(a1, 2, 16); a1 += __shfl_down(a1, 1, 16);
        if (has2) {
            a2 += __shfl_down(a2, 8, 16); a2 += __shfl_down(a2, 4, 16);
            a2 += __shfl_down(a2, 2, 16); a2 += __shfl_down(a2, 1, 16);
        }
        if (cb == 0) {
            wv = myY + a1;
            if (has2) w2v = myY2 + a2;
        }
    }

    // ---- TF-gene epilogue (own 64 rows; 16 threads/gene, 4 h-outputs each) ----
    if (cb == 0) {
        sS[r]  = sSz[r] + wv;
        sS2[r] = has2 ? (1.f + w2v) : 1.f;
    }
    __syncthreads();
    const float s = sS[r], s2 = sS2[r];
    float a0 = 0.f, a1e = 0.f;
#pragma unroll
    for (int oo = 0; oo < 4; ++oo) {
        int o = cb * 4 + oo;
        float pre = fmaf(s, sv1[o], fmaf(s2, su1[o], sb1s[o]));
        float h = fmaxf(pre, 0.f);
        a0  = fmaf(sw20[o], h, a0);
        a1e = fmaf(sw21[o], h, a1e);
    }
    a0  += __shfl_down(a0, 8, 16);  a0  += __shfl_down(a0, 4, 16);
    a0  += __shfl_down(a0, 2, 16);  a0  += __shfl_down(a0, 1, 16);
    a1e += __shfl_down(a1e, 8, 16); a1e += __shfl_down(a1e, 4, 16);
    a1e += __shfl_down(a1e, 2, 16); a1e += __shfl_down(a1e, 1, 16);
    if (cb == 0) {
        int g = tfs_own[r];
        float mu = a0 + sb2v[0];
        float x  = a1e + sb2v[1];
        float sp = fmaxf(x, 0.f) + log1pf(expf(-fabsf(x)));
        out[c * TGN + g]            = mu;
        out[CC * TGN + c * TGN + g] = sp + 1e-6f;
    }
}

extern "C" void kernel_launch(void* const* d_in, const int* in_sizes, int n_in,
                              void* d_out, int out_size, void* d_ws, size_t ws_size,
                              hipStream_t stream)
{
    const float* z   = (const float*)d_in[0];
    const float* grn = (const float*)d_in[1];
    const int*   tf  = (const int*)d_in[2];
    const float* wz  = (const float*)d_in[4];
    const float* bz  = (const float*)d_in[5];
    const float* w1  = (const float*)d_in[6];
    const float* b1  = (const float*)d_in[7];
    const float* w2  = (const float*)d_in[8];
    const float* b2  = (const float*)d_in[9];
    float* out = (float*)d_out;

    char* ws = (char*)d_ws;
    unsigned int* A2 = (unsigned int*)ws;              // 4 MB (bf16 A_S, swizzled)
    float* y    = (float*)(ws + 4194304);
    float* y2   = (float*)(ws + 4210688);
    float* wX   = (float*)(ws + 4227072);              // 16 KB exchange
    float* w2X  = (float*)(ws + 4243456);
    unsigned int* cnt = (unsigned int*)(ws + 4259840); // 8 counters, 64B apart

    prep_kernel<<<PB + 64 + 1, 256, 0, stream>>>(
        z, grn, tf, wz, bz, w1, b1, w2, b2, out, A2, y, y2, cnt);

    solve_kernel<<<CC * QB, 1024, 0, stream>>>(
        z, tf, wz, bz, w1, b1, w2, b2, out, A2, y, y2, wX, w2X, cnt);
}